// Round 4
// baseline (311.356 us; speedup 1.0000x reference)
//
#include <hip/hip_runtime.h>

#define N_STFT 1025
#define N_MELS 128
#define BATCH 4
#define TIME 1024
#define MAX_ITER 20

// Extract per-frequency sparse filterbank structure: each fb row f has at most
// 2 nonzeros at adjacent mel indices (m0, m0+1) — triangular filters.
// One wave per f row; ballot-scan replaces a serial 128-iteration loop.
__global__ void imel_prep(const float* __restrict__ fb, int* __restrict__ m0f,
                          float* __restrict__ w0a, float* __restrict__ w1a) {
  const int w = threadIdx.x >> 6, l = threadIdx.x & 63;
  const int f = blockIdx.x * 4 + w;
  if (f >= N_STFT) return;
  const float* row = fb + (size_t)f * N_MELS;
  const unsigned long long mlo = __ballot(row[l] != 0.0f);
  const unsigned long long mhi = __ballot(row[l + 64] != 0.0f);
  if (l == 0) {
    int m0 = mlo ? __builtin_ctzll(mlo)
                 : (mhi ? 64 + __builtin_ctzll(mhi) : 0);
    if (m0 > N_MELS - 2) m0 = N_MELS - 2;   // all-zero rows (f=0, f=1024) -> w=0
    m0f[f] = m0;
    w0a[f] = row[m0];
    w1a[f] = row[m0 + 1];
  }
}

// 512-thread blocks (8 waves) handle 4 rows; each row split across 2 waves,
// lane chunk = 8 contiguous freqs. 1024 blocks -> 32 waves/CU (VGPR<=64).
//
// Round-3 lesson: LDS is bound by ELEMENT traffic (~44-85 B/cyc/CU), not bank
// skew. m0(f) is monotone and advances <=1 per bin, so each 8-bin chunk spans
// only 1-6 distinct mels -> run-compact both directions:
//   scatter: register partials (a0->m_cur, a1->m_cur+1), flush one i32
//            fixed-point atomic per segment boundary (~383 elems/row vs 2050)
//   gather:  on advance, d0=d1 (register) + 1 fresh read (~510 vs 2050)
//   single P array (no replicas): diff phase 384 elems vs 1152
__global__ __launch_bounds__(512, 8) void imel_main(
    const float* __restrict__ melspec, const float* __restrict__ spec_init,
    const int* __restrict__ m0f, const float* __restrict__ w0a,
    const float* __restrict__ w1a, float* __restrict__ out) {
  __shared__ int   s_Pi[4][N_MELS];    // fixed-point 2^24 accumulator
  __shared__ float s_diff[4][N_MELS];
  __shared__ float s_out[4][1060];     // swizzle-padded: idx = f + (f>>5)

  const int tid = threadIdx.x;
  const int w   = tid >> 6;        // wave 0..7
  const int l   = tid & 63;
  const int row = w >> 1;          // local row 0..3
  const int h   = w & 1;           // freq half
  const int c   = h * 64 + l;      // chunk 0..127 (8 freqs each)
  const int blk = blockIdx.x;
  const int b   = blk >> 8;
  const int t0  = (blk & 255) << 2;
  const int t   = t0 + row;

  const float SCALE = 16777216.0f;           // 2^24 fixed point
  const float INV_SCALE = 1.0f / 16777216.0f;

  // lane owns contiguous f in [8c, 8c+8); chunk 127 also owns f=1024
  float rs[9], rb[9], rw0[9], rw1[9];        // rw* pre-scaled by 2^24
  int rm0[9];

  const float* srow = spec_init + (size_t)(b * TIME + t) * N_STFT;
#pragma unroll
  for (int k = 0; k < 9; ++k) {
    const int f = (c << 3) + k;
    const bool ok = (k < 8) || (c == 127);
    if (ok) {
      rs[k] = srow[f];
      rm0[k] = m0f[f];
      rw0[k] = w0a[f] * SCALE;
      rw1[k] = w1a[f] * SCALE;
    } else {
      rs[k] = 0.f; rm0[k] = 0; rw0[k] = 0.f; rw1[k] = 0.f;
    }
    rb[k] = 0.f;
  }

  // diff-phase role: thread -> (row dr, mel dm)
  const int dr = tid >> 7, dm = tid & 127;
  const float melD = melspec[((size_t)b * N_MELS + dm) * TIME + t0 + dr];

  s_Pi[dr][dm] = 0;
  __syncthreads();

  // grad prefactor (negated) with the 2^-24 unscale folded in (rw* carry 2^24)
  const float GRAD_C = (-2.0f / (BATCH * TIME)) * INV_SCALE;

  for (int it = 0; it < MAX_ITER; ++it) {
    // ---- forward: run-compacted fixed-point scatter ----
    {
      int m_cur = rm0[0];
      float a0 = 0.f, a1 = 0.f;
#pragma unroll
      for (int k = 0; k < 9; ++k) {
        if (k < 8 || c == 127) {
          const bool adv = (rm0[k] != m_cur);           // advances by exactly 1
          if (adv) atomicAdd(&s_Pi[row][m_cur], __float2int_rn(a0));
          const float na0 = (adv ? a1 : a0) + rs[k] * rw0[k];
          a1 = (adv ? 0.f : a1) + rs[k] * rw1[k];
          a0 = na0;
          m_cur = rm0[k];
        }
      }
      atomicAdd(&s_Pi[row][m_cur],     __float2int_rn(a0));
      atomicAdd(&s_Pi[row][m_cur + 1], __float2int_rn(a1));
    }
    __syncthreads();
    // ---- diff = mel - P; reset P for next iteration ----
    s_diff[dr][dm] = melD - (float)s_Pi[dr][dm] * INV_SCALE;
    s_Pi[dr][dm] = 0;
    __syncthreads();
    // ---- backward: run-compacted gather + momentum update + clamp ----
    {
      int m_prev = rm0[0];
      float d0 = s_diff[row][m_prev];
      float d1 = s_diff[row][m_prev + 1];
#pragma unroll
      for (int k = 0; k < 9; ++k) {
        if (k < 8 || c == 127) {
          if (rm0[k] != m_prev) {
            d0 = d1;
            d1 = s_diff[row][rm0[k] + 1];
            m_prev = rm0[k];
          }
          const float g = GRAD_C * (d0 * rw0[k] + d1 * rw1[k]);
          rb[k] = 0.9f * rb[k] + g;
          const float s = rs[k] - 0.3f * rb[k];
          rs[k] = s > 0.f ? s : 0.f;
        }
      }
    }
    // next scatter hits s_Pi (reset + synced); s_diff rewrite is gated by the
    // scatter-phase __syncthreads -> 2 barriers per iteration total
  }

  // ---- epilogue: transpose (f-major regs) -> (B, F, T) via swizzled LDS ----
#pragma unroll
  for (int k = 0; k < 9; ++k) {
    if (k < 8 || c == 127) {
      const int f = (c << 3) + k;
      s_out[row][f + (f >> 5)] = rs[k];
    }
  }
  __syncthreads();

  const int tl = tid & 3;    // t offset within the block's 4 rows
  const int fg = tid >> 2;   // 128 f phases
  float* obase = out + (size_t)b * N_STFT * TIME + t0 + tl;
  for (int f = fg; f < N_STFT; f += 128) {
    obase[(size_t)f * TIME] = s_out[tl][f + (f >> 5)];
  }
}

extern "C" void kernel_launch(void* const* d_in, const int* in_sizes, int n_in,
                              void* d_out, int out_size, void* d_ws, size_t ws_size,
                              hipStream_t stream) {
  const float* melspec = (const float*)d_in[0];
  const float* spec_init = (const float*)d_in[1];
  const float* fb = (const float*)d_in[2];
  float* out = (float*)d_out;

  int* m0f = (int*)d_ws;                          // 1025 ints
  float* w0a = (float*)((char*)d_ws + 5120);      // 1025 floats
  float* w1a = (float*)((char*)d_ws + 10240);     // 1025 floats

  imel_prep<<<dim3(257), dim3(256), 0, stream>>>(fb, m0f, w0a, w1a);
  imel_main<<<dim3(1024), dim3(512), 0, stream>>>(melspec, spec_init, m0f, w0a, w1a, out);
}

// Round 5
// 127.141 us; speedup vs baseline: 2.4489x; 2.4489x over previous
//
#include <hip/hip_runtime.h>

#define N_STFT 1025
#define N_MELS 128
#define BATCH 4
#define TIME 1024
#define MAX_ITER 20

// Extract per-frequency sparse filterbank structure: each fb row f has at most
// 2 nonzeros at adjacent mel indices (m0, m0+1) — triangular filters.
// One wave per f row; ballot-scan replaces a serial 128-iteration loop.
__global__ void imel_prep(const float* __restrict__ fb, int* __restrict__ m0f,
                          float* __restrict__ w0a, float* __restrict__ w1a) {
  const int w = threadIdx.x >> 6, l = threadIdx.x & 63;
  const int f = blockIdx.x * 4 + w;
  if (f >= N_STFT) return;
  const float* row = fb + (size_t)f * N_MELS;
  const unsigned long long mlo = __ballot(row[l] != 0.0f);
  const unsigned long long mhi = __ballot(row[l + 64] != 0.0f);
  if (l == 0) {
    int m0 = mlo ? __builtin_ctzll(mlo)
                 : (mhi ? 64 + __builtin_ctzll(mhi) : 0);
    if (m0 > N_MELS - 2) m0 = N_MELS - 2;   // all-zero rows (f=0, f=1024) -> w=0
    m0f[f] = m0;
    w0a[f] = row[m0];
    w1a[f] = row[m0 + 1];
  }
}

// 1024-thread blocks (16 waves) handle 4 rows; each row split across 4 waves,
// lane owns 4 contiguous freqs. Grid 1024 -> 2 blocks/CU resident = 32
// waves/CU (full occupancy).
//
// Round-4 lesson: __launch_bounds__(.,8) caps the budget at 64 VGPR/lane; the
// 8-bin/lane compacted state (~60 live regs) spilled to scratch -> 648 MB of
// HBM spill traffic, 250us. 4 bins/lane cuts array state to ~25 regs (~40
// live) -> guaranteed no spill, same compacted LDS element traffic:
//   scatter: register partials (a0->m_cur, a1->m_cur+1), flush one i32
//            fixed-point atomic per mel-segment boundary (m0 monotone, step<=1)
//   gather:  on advance, d0=d1 (register shift) + 1 fresh diff read
__global__ __launch_bounds__(1024, 8) void imel_main(
    const float* __restrict__ melspec, const float* __restrict__ spec_init,
    const int* __restrict__ m0f, const float* __restrict__ w0a,
    const float* __restrict__ w1a, float* __restrict__ out) {
  __shared__ int   s_Pi[4][N_MELS];    // fixed-point 2^24 accumulator
  __shared__ float s_diff[4][N_MELS];
  __shared__ float s_out[4][1060];     // swizzle-padded: idx = f + (f>>5)

  const int tid = threadIdx.x;
  const int w   = tid >> 6;        // wave 0..15
  const int l   = tid & 63;
  const int row = w >> 2;          // local row 0..3
  const int q   = w & 3;           // quarter of the freq axis
  const int c   = q * 64 + l;      // chunk 0..255 (4 freqs each)
  const int blk = blockIdx.x;
  const int b   = blk >> 8;
  const int t0  = (blk & 255) << 2;
  const int t   = t0 + row;

  const float SCALE = 16777216.0f;           // 2^24 fixed point
  const float INV_SCALE = 1.0f / 16777216.0f;

  // lane owns contiguous f in [4c, 4c+4); chunk 255 also owns f=1024
  float rs[5], rb[5], rw0[5], rw1[5];        // rw* pre-scaled by 2^24
  int rm0[5];

  const float* srow = spec_init + (size_t)(b * TIME + t) * N_STFT;
#pragma unroll
  for (int k = 0; k < 5; ++k) {
    const int f = (c << 2) + k;
    const bool ok = (k < 4) || (c == 255);
    if (ok) {
      rs[k] = srow[f];
      rm0[k] = m0f[f];
      rw0[k] = w0a[f] * SCALE;
      rw1[k] = w1a[f] * SCALE;
    } else {
      rs[k] = 0.f; rm0[k] = 0; rw0[k] = 0.f; rw1[k] = 0.f;
    }
    rb[k] = 0.f;
  }

  // diff-phase role: threads 0..511 -> (row dr, mel dm)
  const int dr = (tid >> 7) & 3, dm = tid & 127;
  const bool dact = tid < 512;
  const float melD = dact ? melspec[((size_t)b * N_MELS + dm) * TIME + t0 + dr]
                          : 0.f;

  if (dact) s_Pi[dr][dm] = 0;
  __syncthreads();

  // grad prefactor (negated) with the 2^-24 unscale folded in (rw* carry 2^24)
  const float GRAD_C = (-2.0f / (BATCH * TIME)) * INV_SCALE;

  for (int it = 0; it < MAX_ITER; ++it) {
    // ---- forward: run-compacted fixed-point scatter ----
    {
      int m_cur = rm0[0];
      float a0 = 0.f, a1 = 0.f;
#pragma unroll
      for (int k = 0; k < 5; ++k) {
        if (k < 4 || c == 255) {
          const bool adv = (rm0[k] != m_cur);           // advances by exactly 1
          if (adv) atomicAdd(&s_Pi[row][m_cur], __float2int_rn(a0));
          const float na0 = (adv ? a1 : a0) + rs[k] * rw0[k];
          a1 = (adv ? 0.f : a1) + rs[k] * rw1[k];
          a0 = na0;
          m_cur = rm0[k];
        }
      }
      atomicAdd(&s_Pi[row][m_cur],     __float2int_rn(a0));
      atomicAdd(&s_Pi[row][m_cur + 1], __float2int_rn(a1));
    }
    __syncthreads();
    // ---- diff = mel - P; reset P for next iteration ----
    if (dact) {
      s_diff[dr][dm] = melD - (float)s_Pi[dr][dm] * INV_SCALE;
      s_Pi[dr][dm] = 0;
    }
    __syncthreads();
    // ---- backward: run-compacted gather + momentum update + clamp ----
    {
      int m_prev = rm0[0];
      float d0 = s_diff[row][m_prev];
      float d1 = s_diff[row][m_prev + 1];
#pragma unroll
      for (int k = 0; k < 5; ++k) {
        if (k < 4 || c == 255) {
          if (rm0[k] != m_prev) {
            d0 = d1;
            d1 = s_diff[row][rm0[k] + 1];
            m_prev = rm0[k];
          }
          const float g = GRAD_C * (d0 * rw0[k] + d1 * rw1[k]);
          rb[k] = 0.9f * rb[k] + g;
          const float s = rs[k] - 0.3f * rb[k];
          rs[k] = s > 0.f ? s : 0.f;
        }
      }
    }
    // next scatter hits s_Pi (reset + synced); s_diff rewrite is gated by the
    // scatter-phase __syncthreads -> 2 barriers per iteration total
  }

  // ---- epilogue: transpose (f-major regs) -> (B, F, T) via swizzled LDS ----
#pragma unroll
  for (int k = 0; k < 5; ++k) {
    if (k < 4 || c == 255) {
      const int f = (c << 2) + k;
      s_out[row][f + (f >> 5)] = rs[k];
    }
  }
  __syncthreads();

  const int tl = tid & 3;    // t offset within the block's 4 rows
  const int fg = tid >> 2;   // 256 f phases
  float* obase = out + (size_t)b * N_STFT * TIME + t0 + tl;
  for (int f = fg; f < N_STFT; f += 256) {
    obase[(size_t)f * TIME] = s_out[tl][f + (f >> 5)];
  }
}

extern "C" void kernel_launch(void* const* d_in, const int* in_sizes, int n_in,
                              void* d_out, int out_size, void* d_ws, size_t ws_size,
                              hipStream_t stream) {
  const float* melspec = (const float*)d_in[0];
  const float* spec_init = (const float*)d_in[1];
  const float* fb = (const float*)d_in[2];
  float* out = (float*)d_out;

  int* m0f = (int*)d_ws;                          // 1025 ints
  float* w0a = (float*)((char*)d_ws + 5120);      // 1025 floats
  float* w1a = (float*)((char*)d_ws + 10240);     // 1025 floats

  imel_prep<<<dim3(257), dim3(256), 0, stream>>>(fb, m0f, w0a, w1a);
  imel_main<<<dim3(1024), dim3(1024), 0, stream>>>(melspec, spec_init, m0f, w0a, w1a, out);
}

// Round 6
// 117.100 us; speedup vs baseline: 2.6589x; 1.0858x over previous
//
#include <hip/hip_runtime.h>

#define N_STFT 1025
#define N_MELS 128
#define BATCH 4
#define TIME 1024
#define MAX_ITER 20

// Extract per-frequency sparse filterbank structure: each fb row f has at most
// 2 nonzeros at adjacent mel indices (m0, m0+1) — triangular filters.
// One wave per f row; ballot-scan replaces a serial 128-iteration loop.
__global__ void imel_prep(const float* __restrict__ fb, int* __restrict__ m0f,
                          float* __restrict__ w0a, float* __restrict__ w1a) {
  const int w = threadIdx.x >> 6, l = threadIdx.x & 63;
  const int f = blockIdx.x * 4 + w;
  if (f >= N_STFT) return;
  const float* row = fb + (size_t)f * N_MELS;
  const unsigned long long mlo = __ballot(row[l] != 0.0f);
  const unsigned long long mhi = __ballot(row[l + 64] != 0.0f);
  if (l == 0) {
    int m0 = mlo ? __builtin_ctzll(mlo)
                 : (mhi ? 64 + __builtin_ctzll(mhi) : 0);
    if (m0 > N_MELS - 2) m0 = N_MELS - 2;   // all-zero rows (f=0, f=1024) -> w=0
    m0f[f] = m0;
    w0a[f] = row[m0];
    w1a[f] = row[m0 + 1];
  }
}

// 1024-thread blocks (16 waves) handle 4 rows; each row split across 4 waves,
// lane owns 4 contiguous freqs (f = 4c..4c+3). Grid 1024 -> 2 blocks/CU = 32
// waves/CU. f=1024 has an all-zero fb row (up-slope hits 0 exactly at f_max)
// -> pure passthrough, handled only in init/epilogue; the hot loop is a
// branch-uniform k=0..3.
//
// Round-5 lesson: VGPR_Count=32 meant the compiler re-materialized all
// loop-invariant work (cmp, exec masks, LDS addresses) every iteration, and
// the backward cndmask->ds_read serial chain left 41% of issue slots idle.
// This version hoists the static structure (adv masks in SGPRs, 4 invariant
// LDS addresses) and issues all 8 backward diff reads upfront at static
// addresses: P (int, fixed-point 2^24) and diff (float) share one LDS array
// so (diff[rm], diff[rm+1]) is one ds_read2_b32 off the scatter's address reg.
__global__ __launch_bounds__(1024, 8) void imel_main(
    const float* __restrict__ melspec, const float* __restrict__ spec_init,
    const int* __restrict__ m0f, const float* __restrict__ w0a,
    const float* __restrict__ w1a, float* __restrict__ out) {
  __shared__ int   s_PD[4][2 * N_MELS];  // [row][0..127]=P fixed-point,
                                         // [row][128..255]=diff (float bits)
  __shared__ float s_out[4][1060];       // swizzle-padded: idx = f + (f>>5)

  const int tid = threadIdx.x;
  const int w   = tid >> 6;        // wave 0..15
  const int l   = tid & 63;
  const int row = w >> 2;          // local row 0..3
  const int q   = w & 3;           // quarter of the freq axis
  const int c   = q * 64 + l;      // chunk 0..255 (4 freqs each)
  const int blk = blockIdx.x;
  const int b   = blk >> 8;
  const int t0  = (blk & 255) << 2;
  const int t   = t0 + row;

  const float SCALE = 16777216.0f;            // 2^24 fixed point
  const float INV_SCALE = 1.0f / 16777216.0f;

  // per-lane static structure, f = 4c + k
  float rs[4], rb[4], rw0[4], rw1[4];         // rw* pre-scaled by 2^24
  int rm[4];

  const float* srow = spec_init + (size_t)(b * TIME + t) * N_STFT;
#pragma unroll
  for (int k = 0; k < 4; ++k) {
    const int f = (c << 2) + k;
    rs[k]  = srow[f];
    rm[k]  = m0f[f];
    rw0[k] = w0a[f] * SCALE;
    rw1[k] = w1a[f] * SCALE;
    rb[k]  = 0.f;
  }
  const bool tail = (c == 255);
  const float rtail = tail ? srow[1024] : 0.f;   // f=1024: zero fb row -> copy

  // loop-invariant advance flags (compile to wave masks in SGPR pairs)
  const bool adv1 = (rm[1] != rm[0]);
  const bool adv2 = (rm[2] != rm[1]);
  const bool adv3 = (rm[3] != rm[2]);

  // diff-phase role: threads 0..511 -> (row dr, mel dm)
  const int dr = (tid >> 7) & 3, dm = tid & 127;
  const bool dact = tid < 512;
  // fold grad prefactor GRAD_C = (-2/(B*T))*INV_SCALE into the stored diff:
  //   diff' = GRAD_C*mel - (GRAD_C*INV_SCALE)*P_fixed
  const float GRAD_C = (-2.0f / (BATCH * TIME)) * INV_SCALE;
  const float NC2 = -GRAD_C * INV_SCALE;   // positive
  const float melG = dact
      ? GRAD_C * melspec[((size_t)b * N_MELS + dm) * TIME + t0 + dr] : 0.f;

  if (dact) s_PD[dr][dm] = 0;
  __syncthreads();

  for (int it = 0; it < MAX_ITER; ++it) {
    // ---- forward: run-compacted fixed-point scatter (static addresses) ----
    {
      float a0 = rs[0] * rw0[0];
      float a1 = rs[0] * rw1[0];
      if (adv1) atomicAdd(&s_PD[row][rm[0]], __float2int_rn(a0));
      a0 = (adv1 ? a1 : a0) + rs[1] * rw0[1];
      a1 = (adv1 ? 0.f : a1) + rs[1] * rw1[1];
      if (adv2) atomicAdd(&s_PD[row][rm[1]], __float2int_rn(a0));
      a0 = (adv2 ? a1 : a0) + rs[2] * rw0[2];
      a1 = (adv2 ? 0.f : a1) + rs[2] * rw1[2];
      if (adv3) atomicAdd(&s_PD[row][rm[2]], __float2int_rn(a0));
      a0 = (adv3 ? a1 : a0) + rs[3] * rw0[3];
      a1 = (adv3 ? 0.f : a1) + rs[3] * rw1[3];
      atomicAdd(&s_PD[row][rm[3]],     __float2int_rn(a0));
      atomicAdd(&s_PD[row][rm[3] + 1], __float2int_rn(a1));
    }
    __syncthreads();
    // ---- diff' = GRAD_C*(mel - P); reset P ----
    if (dact) {
      const float pf = (float)s_PD[dr][dm];
      s_PD[dr][N_MELS + dm] = __float_as_int(fmaf(pf, NC2, melG));
      s_PD[dr][dm] = 0;
    }
    __syncthreads();
    // ---- backward: 8 static-address reads upfront (ds_read2-friendly),
    //      then pure register arithmetic (no select chain) ----
    float d0[4], d1[4];
#pragma unroll
    for (int k = 0; k < 4; ++k) {
      d0[k] = __int_as_float(s_PD[row][N_MELS + rm[k]]);
      d1[k] = __int_as_float(s_PD[row][N_MELS + rm[k] + 1]);
    }
#pragma unroll
    for (int k = 0; k < 4; ++k) {
      const float g = fmaf(d1[k], rw1[k], d0[k] * rw0[k]);  // includes GRAD_C
      rb[k] = fmaf(0.9f, rb[k], g);
      rs[k] = fmaxf(fmaf(-0.3f, rb[k], rs[k]), 0.f);
    }
    // 2 barriers/iter: scatter(i+1) precedes the post-scatter barrier, which
    // guarantees backward(i)'s diff reads completed before diff(i+1) rewrite
  }

  // ---- epilogue: transpose (f-major regs) -> (B, F, T) via swizzled LDS ----
#pragma unroll
  for (int k = 0; k < 4; ++k) {
    const int f = (c << 2) + k;
    s_out[row][f + (f >> 5)] = rs[k];
  }
  if (tail) s_out[row][1056] = rtail;    // f=1024 -> 1024 + (1024>>5)
  __syncthreads();

  const int tl = tid & 3;    // t offset within the block's 4 rows
  const int fg = tid >> 2;   // 256 f phases
  float* obase = out + (size_t)b * N_STFT * TIME + t0 + tl;
  for (int f = fg; f < N_STFT; f += 256) {
    obase[(size_t)f * TIME] = s_out[tl][f + (f >> 5)];
  }
}

extern "C" void kernel_launch(void* const* d_in, const int* in_sizes, int n_in,
                              void* d_out, int out_size, void* d_ws, size_t ws_size,
                              hipStream_t stream) {
  const float* melspec = (const float*)d_in[0];
  const float* spec_init = (const float*)d_in[1];
  const float* fb = (const float*)d_in[2];
  float* out = (float*)d_out;

  int* m0f = (int*)d_ws;                          // 1025 ints
  float* w0a = (float*)((char*)d_ws + 5120);      // 1025 floats
  float* w1a = (float*)((char*)d_ws + 10240);     // 1025 floats

  imel_prep<<<dim3(257), dim3(256), 0, stream>>>(fb, m0f, w0a, w1a);
  imel_main<<<dim3(1024), dim3(1024), 0, stream>>>(melspec, spec_init, m0f, w0a, w1a, out);
}